// Round 1
// baseline (76.718 us; speedup 1.0000x reference)
//
#include <hip/hip_runtime.h>
#include <math.h>

namespace {

constexpr int kB = 8;
constexpr int kK = 4096;
constexpr int kC = 1024;
constexpr int kL = 64;            // chunk length along K
constexpr int kNC = kK / kL;      // 64 chunks
constexpr int kTPB = 256;         // 4 channels/thread -> 256 threads cover C=1024

constexpr float kClamp = 1.0e4f;
constexpr float kMinD = 0.001f;
constexpr float kMaxD = 0.999f;
constexpr float kEps = 1e-6f;

__device__ __forceinline__ float sanitize(float x) {
  // nan -> 0, +/-inf -> clamp, then clip to [-1e4, 1e4]
  x = (x != x) ? 0.0f : x;
  return fminf(kClamp, fmaxf(-kClamp, x));
}

__device__ __forceinline__ float softplusf(float x) {
  // numerically-stable log1p(exp(x))
  return fmaxf(x, 0.0f) + log1pf(expf(-fabsf(x)));
}

__device__ __forceinline__ float decay_of(float logit) {
  float sg = 1.0f / (1.0f + expf(-logit));
  return kMinD + (kMaxD - kMinD) * sg;
}

// Pass 1: per (b, chunk) compute the zero-init local scan's final value (carry).
__global__ __launch_bounds__(kTPB) void k_carry(
    const float* __restrict__ tokens, const float* __restrict__ dlog,
    const float* __restrict__ igr, const float* __restrict__ sbias,
    float* __restrict__ carry) {
  const int b = blockIdx.x / kNC;
  const int j = blockIdx.x % kNC;
  const int c0 = threadIdx.x * 4;

  const float4 dl = *reinterpret_cast<const float4*>(dlog + c0);
  const float4 ig = *reinterpret_cast<const float4*>(igr + c0);
  const float4 sb = *reinterpret_cast<const float4*>(sbias + c0);

  const float d0 = decay_of(dl.x), d1 = decay_of(dl.y);
  const float d2 = decay_of(dl.z), d3 = decay_of(dl.w);
  const float g0 = softplusf(ig.x) + kEps, g1 = softplusf(ig.y) + kEps;
  const float g2 = softplusf(ig.z) + kEps, g3 = softplusf(ig.w) + kEps;
  // b_t = (1-d)*(g*x + bias) = a*x + bb
  const float a0 = (1.0f - d0) * g0, a1 = (1.0f - d1) * g1;
  const float a2 = (1.0f - d2) * g2, a3 = (1.0f - d3) * g3;
  const float bb0 = (1.0f - d0) * sb.x, bb1 = (1.0f - d1) * sb.y;
  const float bb2 = (1.0f - d2) * sb.z, bb3 = (1.0f - d3) * sb.w;

  const float* tp = tokens + (((size_t)b * kK) + (size_t)j * kL) * kC + c0;

  float s0 = 0.0f, s1 = 0.0f, s2 = 0.0f, s3 = 0.0f;
#pragma unroll 8
  for (int i = 0; i < kL; ++i) {
    const float4 x = *reinterpret_cast<const float4*>(tp + (size_t)i * kC);
    s0 = fmaf(d0, s0, fmaf(a0, sanitize(x.x), bb0));
    s1 = fmaf(d1, s1, fmaf(a1, sanitize(x.y), bb1));
    s2 = fmaf(d2, s2, fmaf(a2, sanitize(x.z), bb2));
    s3 = fmaf(d3, s3, fmaf(a3, sanitize(x.w), bb3));
  }
  float4 outv = make_float4(s0, s1, s2, s3);
  *reinterpret_cast<float4*>(carry + ((size_t)b * kNC + j) * kC + c0) = outv;
}

// Pass 2: per (b,c) scan the 64 chunk carries; emit chunk start states and
// the final state output.
__global__ __launch_bounds__(256) void k_prefix(
    const float* __restrict__ carry, const float* __restrict__ state,
    const float* __restrict__ dlog, float* __restrict__ sstart,
    float* __restrict__ final_out) {
  const int idx = blockIdx.x * blockDim.x + threadIdx.x;  // [0, B*C)
  const int b = idx / kC;
  const int c = idx - b * kC;
  const float d = decay_of(dlog[c]);
  float dL = d;
#pragma unroll
  for (int i = 0; i < 6; ++i) dL *= dL;  // d^64
  float s = state[idx];
  for (int j = 0; j < kNC; ++j) {
    const size_t o = ((size_t)b * kNC + j) * kC + c;
    sstart[o] = s;
    s = fmaf(dL, s, carry[o]);
  }
  final_out[idx] = s;
}

// Pass 3: re-scan each chunk from its true start state; write gained outputs.
__global__ __launch_bounds__(kTPB) void k_out(
    const float* __restrict__ tokens, const float* __restrict__ dlog,
    const float* __restrict__ igr, const float* __restrict__ ogr,
    const float* __restrict__ sbias, const float* __restrict__ sstart,
    float* __restrict__ out) {
  const int b = blockIdx.x / kNC;
  const int j = blockIdx.x % kNC;
  const int c0 = threadIdx.x * 4;

  const float4 dl = *reinterpret_cast<const float4*>(dlog + c0);
  const float4 ig = *reinterpret_cast<const float4*>(igr + c0);
  const float4 og = *reinterpret_cast<const float4*>(ogr + c0);
  const float4 sb = *reinterpret_cast<const float4*>(sbias + c0);

  const float d0 = decay_of(dl.x), d1 = decay_of(dl.y);
  const float d2 = decay_of(dl.z), d3 = decay_of(dl.w);
  const float g0 = softplusf(ig.x) + kEps, g1 = softplusf(ig.y) + kEps;
  const float g2 = softplusf(ig.z) + kEps, g3 = softplusf(ig.w) + kEps;
  const float a0 = (1.0f - d0) * g0, a1 = (1.0f - d1) * g1;
  const float a2 = (1.0f - d2) * g2, a3 = (1.0f - d3) * g3;
  const float bb0 = (1.0f - d0) * sb.x, bb1 = (1.0f - d1) * sb.y;
  const float bb2 = (1.0f - d2) * sb.z, bb3 = (1.0f - d3) * sb.w;
  const float o0 = softplusf(og.x) + kEps, o1 = softplusf(og.y) + kEps;
  const float o2 = softplusf(og.z) + kEps, o3 = softplusf(og.w) + kEps;

  const float4 sinit =
      *reinterpret_cast<const float4*>(sstart + ((size_t)b * kNC + j) * kC + c0);
  float s0 = sinit.x, s1 = sinit.y, s2 = sinit.z, s3 = sinit.w;

  const float* tp = tokens + (((size_t)b * kK) + (size_t)j * kL) * kC + c0;
  float* op = out + (((size_t)b * kK) + (size_t)j * kL) * kC + c0;

#pragma unroll 8
  for (int i = 0; i < kL; ++i) {
    const float4 x = *reinterpret_cast<const float4*>(tp + (size_t)i * kC);
    s0 = fmaf(d0, s0, fmaf(a0, sanitize(x.x), bb0));
    s1 = fmaf(d1, s1, fmaf(a1, sanitize(x.y), bb1));
    s2 = fmaf(d2, s2, fmaf(a2, sanitize(x.z), bb2));
    s3 = fmaf(d3, s3, fmaf(a3, sanitize(x.w), bb3));
    float4 y = make_float4(o0 * s0, o1 * s1, o2 * s2, o3 * s3);
    *reinterpret_cast<float4*>(op + (size_t)i * kC) = y;
  }
}

}  // namespace

extern "C" void kernel_launch(void* const* d_in, const int* in_sizes, int n_in,
                              void* d_out, int out_size, void* d_ws, size_t ws_size,
                              hipStream_t stream) {
  const float* tokens = (const float*)d_in[0];
  const float* state  = (const float*)d_in[1];
  const float* dlog   = (const float*)d_in[2];
  const float* igr    = (const float*)d_in[3];
  const float* ogr    = (const float*)d_in[4];
  const float* sbias  = (const float*)d_in[5];

  float* out = (float*)d_out;                       // [B,K,C] outputs
  float* final_out = out + (size_t)kB * kK * kC;    // [B,C] final state

  float* carry  = (float*)d_ws;                     // B*NC*C floats (2 MiB)
  float* sstart = carry + (size_t)kB * kNC * kC;    // B*NC*C floats (2 MiB)

  k_carry<<<dim3(kB * kNC), kTPB, 0, stream>>>(tokens, dlog, igr, sbias, carry);
  k_prefix<<<dim3((kB * kC) / 256), 256, 0, stream>>>(carry, state, dlog, sstart,
                                                      final_out);
  k_out<<<dim3(kB * kNC), kTPB, 0, stream>>>(tokens, dlog, igr, ogr, sbias,
                                             sstart, out);
}